// Round 7
// baseline (156.035 us; speedup 1.0000x reference)
//
#include <hip/hip_runtime.h>

#define NBOX   2048
#define MAXDET 100
#define NIMG   8
#define BLK    512
#define NWAVE  (BLK / 64)   // 8 waves
#define INFI   0x7FFFFFFF
// midpoint(0.3f, nextafterf(0.3f,+inf)) in double:
// RN_f32(inter/denom) > 0.3f  <=>  inter > IOU_MID * denom
// (25-bit mid x 24-bit denom product is exact in f64; tie rounds-to-even to 0.3f -> "false" matches)
#define IOU_MID 0x1.333335p-2

typedef unsigned long long u64;

// padded LDS index for u64 keys: 16 consecutive phys u64 cover all 32 banks once
__device__ __forceinline__ int KP(int i) { return i + (i >> 4); }
#define KEYSZ (NBOX + NBOX / 16)   // 2176 u64 per buffer

__device__ __forceinline__ u64 shflx64(u64 v, int m) {
    int lo = __shfl_xor((int)(unsigned int)v, m, 64);
    int hi = __shfl_xor((int)(unsigned int)(v >> 32), m, 64);
    return ((u64)(unsigned int)hi << 32) | (unsigned int)lo;
}
// bitonic exchange keep-rule: take_max ? max(mine,partner) : min(mine,partner)
__device__ __forceinline__ u64 cmpsel(u64 mine, u64 part, bool take_max) {
    bool agtb = mine > part;
    return (agtb == take_max) ? mine : part;
}

// ---- sort building blocks (thread g owns positions 4g..4g+3 in k0..k3) ----
// in-lane compare-exchange, direction d (true = descending)
#define CX(a, b) { if (d ? ((a) < (b)) : ((a) > (b))) { u64 _t = (a); (a) = (b); (b) = _t; } }
// j=2 then j=1 on the 4 in-lane keys; dcond = descending region for phase k
#define SORT4(dcond) { bool d = (dcond); CX(k0, k2) CX(k1, k3) CX(k0, k1) CX(k2, k3) }
// intra-wave stage j = 4*mm at phase kk: partner lane = lane ^ mm
#define SHFL_STAGE(mm, kk) {                                                  \
    bool tmax = ((g & ((kk) >> 2)) == 0) == ((lane & (mm)) == 0);             \
    k0 = cmpsel(k0, shflx64(k0, (mm)), tmax);                                 \
    k1 = cmpsel(k1, shflx64(k1, (mm)), tmax);                                 \
    k2 = cmpsel(k2, shflx64(k2, (mm)), tmax);                                 \
    k3 = cmpsel(k3, shflx64(k3, (mm)), tmax); }
#define SHFL_RUN_32_1(kk) SHFL_STAGE(32, kk) SHFL_STAGE(16, kk) SHFL_STAGE(8, kk) \
    SHFL_STAGE(4, kk) SHFL_STAGE(2, kk) SHFL_STAGE(1, kk)
// cross-wave stage j = jj at phase kk via LDS buffer BUF (write own 4, barrier, read partner 4)
#define LDS_STAGE(jj, kk, BUF) {                                              \
    int _base = KP(4 * g);                                                    \
    BUF[_base] = k0; BUF[_base + 1] = k1; BUF[_base + 2] = k2; BUF[_base + 3] = k3; \
    __syncthreads();                                                          \
    int _pb = KP((4 * g) ^ (jj));                                             \
    u64 p0 = BUF[_pb], p1 = BUF[_pb + 1], p2 = BUF[_pb + 2], p3 = BUF[_pb + 3]; \
    bool tmax = ((g & ((kk) >> 2)) == 0) == ((g & ((jj) >> 2)) == 0);         \
    k0 = cmpsel(k0, p0, tmax); k1 = cmpsel(k1, p1, tmax);                     \
    k2 = cmpsel(k2, p2, tmax); k3 = cmpsel(k3, p3, tmax); }

__device__ __forceinline__ u64 mkkey(float4 v, float s, int i) {
    bool valid = ((v.z - v.x) >= 25.0f) && ((v.w - v.y) >= 25.0f) && (s >= 0.001f);
    unsigned int sk = valid ? __float_as_uint(s) : 0u;  // scores in [0,1): bits monotone
    return ((u64)sk << 32) | (unsigned int)(~i);
}

#define FOR4(OP) OP(0) OP(1) OP(2) OP(3)

__global__ __launch_bounds__(BLK) void region_extractor_kernel(
    const float* __restrict__ boxes,   // [NIMG, NBOX, 4] xyxy
    const float* __restrict__ scores,  // [NIMG, NBOX]
    float* __restrict__ out)           // [NIMG*MAXDET*5] regions ++ [NIMG*MAXDET] mask
{
    __shared__ u64 kbufA[KEYSZ];                  // 17 KB
    __shared__ u64 kbufB[KEYSZ];                  // 17 KB (double buffer: 1 barrier/LDS stage)
    __shared__ __align__(16) int candI[2][NWAVE]; // parity-buffered per-wave candidate pos
    __shared__ float4 candB[2][NWAVE];            // candidate's box

    const int g    = threadIdx.x;      // 0..511; owns sorted positions 4g..4g+3
    const int lane = g & 63;
    const int wave = g >> 6;
    const int b    = blockIdx.x;
    const float4* bb4 = (const float4*)(boxes + (size_t)b * NBOX * 4);
    const float4* ss4 = (const float4*)(scores + (size_t)b * NBOX);

    // ---- Phase A: build keys in registers (thread g <- boxes 4g..4g+3) ---
    // key = (score_bits << 32) | ~idx : desc sort == (score desc, idx asc); invalid -> hi=0
    float4 sv = ss4[g];
    u64 k0, k1, k2, k3;
    { float4 v = bb4[4 * g + 0]; k0 = mkkey(v, sv.x, 4 * g + 0); }
    { float4 v = bb4[4 * g + 1]; k1 = mkkey(v, sv.y, 4 * g + 1); }
    { float4 v = bb4[4 * g + 2]; k2 = mkkey(v, sv.z, 4 * g + 2); }
    { float4 v = bb4[4 * g + 3]; k3 = mkkey(v, sv.w, 4 * g + 3); }

    // ---- Phase B: bitonic sort, descending; only 6 stages touch LDS ------
    { bool d = true;  CX(k0, k1) }     // k=2: pair (4g,4g+1) desc
    { bool d = false; CX(k2, k3) }     // k=2: pair (4g+2,4g+3) asc
    SORT4((g & 1) == 0)                                        // k=4
    SHFL_STAGE(1, 8)                     SORT4((g & 2) == 0)   // k=8
    SHFL_STAGE(2, 16)  SHFL_STAGE(1, 16) SORT4((g & 4) == 0)   // k=16
    SHFL_STAGE(4, 32)  SHFL_STAGE(2, 32)  SHFL_STAGE(1, 32)  SORT4((g & 8) == 0)
    SHFL_STAGE(8, 64)  SHFL_STAGE(4, 64)  SHFL_STAGE(2, 64)  SHFL_STAGE(1, 64)
    SORT4((g & 16) == 0)
    SHFL_STAGE(16, 128) SHFL_STAGE(8, 128) SHFL_STAGE(4, 128) SHFL_STAGE(2, 128)
    SHFL_STAGE(1, 128) SORT4((g & 32) == 0)
    SHFL_RUN_32_1(256)  SORT4((g & 64) == 0)                   // k=256
    LDS_STAGE(256, 512, kbufA)  SHFL_RUN_32_1(512)  SORT4((g & 128) == 0)
    LDS_STAGE(512, 1024, kbufB) LDS_STAGE(256, 1024, kbufA)
    SHFL_RUN_32_1(1024) SORT4((g & 256) == 0)
    LDS_STAGE(1024, 2048, kbufB) LDS_STAGE(512, 2048, kbufA) LDS_STAGE(256, 2048, kbufB)
    SHFL_RUN_32_1(2048) SORT4(true)    // (4g & 2048)==0 for g<512: final desc merge

    // ---- Phase C: sorted keys are ALREADY in the right lanes; gather boxes
#define DECLB(i) float x1_##i, y1_##i, x2_##i, y2_##i, ar_##i;
    FOR4(DECLB)
    unsigned int alive = 0;  // bit i: sorted pos 4g+i valid & unsuppressed & unprocessed
#define LOADB(i) { unsigned int idx = ~(unsigned int)k##i;                    \
        float4 v = bb4[idx];                                                  \
        x1_##i = v.x; y1_##i = v.y; x2_##i = v.z; y2_##i = v.w;               \
        ar_##i = (v.z - v.x) * (v.w - v.y);                                   \
        if ((unsigned int)(k##i >> 32) != 0u) alive |= (1u << i); }
    FOR4(LOADB)

    float* regions = out;
    float* maskv   = out + (size_t)NIMG * MAXDET * 5;
    int nkept = 0;

    // ---- Phase D: 8-wave greedy NMS, one barrier/iter, payload records ---
    for (int it = 0; ; ++it) {
        int par = it & 1;
        u64 bal = __ballot(alive != 0u);
        if (bal == 0ULL) {
            if (lane == 0) candI[par][wave] = INFI;
        } else {
            int owner = (int)__builtin_ctzll(bal);
            if (lane == owner) {                     // owner posts pos + box together
                int c = (int)__builtin_ctz(alive);
                float bx = x1_0, by = y1_0, bz = x2_0, bw = y2_0;
                if (c == 1) { bx = x1_1; by = y1_1; bz = x2_1; bw = y2_1; }
                if (c == 2) { bx = x1_2; by = y1_2; bz = x2_2; bw = y2_2; }
                if (c == 3) { bx = x1_3; by = y1_3; bz = x2_3; bw = y2_3; }
                candI[par][wave] = 4 * g + c;
                candB[par][wave] = make_float4(bx, by, bz, bw);
            }
        }
        __syncthreads();   // parity buffers make post(it+1) race-free vs readers of (it)

        // preload all 8 records (uniform broadcasts, one latency window),
        // then register tournament -> no dependent LDS read on the chain
        const int4* cp = (const int4*)(&candI[par][0]);
        int4 ca = cp[0], cb = cp[1];
        float4 r0 = candB[par][0], r1 = candB[par][1], r2 = candB[par][2], r3 = candB[par][3];
        float4 r4 = candB[par][4], r5 = candB[par][5], r6 = candB[par][6], r7 = candB[par][7];
        int   i01 = ca.x; float4 b01 = r0; if (ca.y < i01) { i01 = ca.y; b01 = r1; }
        int   i23 = ca.z; float4 b23 = r2; if (ca.w < i23) { i23 = ca.w; b23 = r3; }
        int   i45 = cb.x; float4 b45 = r4; if (cb.y < i45) { i45 = cb.y; b45 = r5; }
        int   i67 = cb.z; float4 b67 = r6; if (cb.w < i67) { i67 = cb.w; b67 = r7; }
        if (i23 < i01) { i01 = i23; b01 = b23; }
        if (i67 < i45) { i45 = i67; b45 = b67; }
        if (i45 < i01) { i01 = i45; b01 = b45; }
        if (i01 == INFI) break;                      // uniform: nothing alive

        float4 L = b01;
        float larea = (L.z - L.x) * (L.w - L.y);

        if (g == 0) {                                // emit kept row
            float* r = regions + ((size_t)(b * MAXDET + nkept)) * 5;
            r[0] = (float)b; r[1] = L.x; r[2] = L.y; r[3] = L.z; r[4] = L.w;
            maskv[b * MAXDET + nkept] = 1.0f;
        }
        nkept++;
        if (nkept >= MAXDET) break;                  // uniform

        // suppression sweep: 4 register IoU tests/lane; leader self-kills (IoU=1)
        unsigned int kill = 0;
#define TESTB(i) {                                                            \
        float iw = fminf(L.z, x2_##i) - fmaxf(L.x, x1_##i);                   \
        float ih = fminf(L.w, y2_##i) - fmaxf(L.y, y1_##i);                   \
        iw = fmaxf(iw, 0.0f); ih = fmaxf(ih, 0.0f);                           \
        float inter = iw * ih;                                                \
        float denom = (larea + ar_##i) - inter; /* ref: (a_j + a_i) - inter */ \
        if ((double)inter > IOU_MID * (double)denom) kill |= (1u << i); }
        FOR4(TESTB)
        alive &= ~kill;
    }

    // ---- Phase E: fill padding rows (d_out is poisoned every launch) -----
    for (int r = nkept + g; r < MAXDET; r += BLK) {
        float* rr = regions + ((size_t)(b * MAXDET + r)) * 5;
        rr[0] = (float)b; rr[1] = 0.0f; rr[2] = 0.0f; rr[3] = 0.0f; rr[4] = 0.0f;
        maskv[b * MAXDET + r] = 0.0f;
    }
}

extern "C" void kernel_launch(void* const* d_in, const int* in_sizes, int n_in,
                              void* d_out, int out_size, void* d_ws, size_t ws_size,
                              hipStream_t stream) {
    const float* boxes  = (const float*)d_in[0];  // [8,2048,4] f32
    const float* scores = (const float*)d_in[1];  // [8,2048]   f32
    float* out = (float*)d_out;                   // 4800 f32: regions(4000) ++ mask(800)
    region_extractor_kernel<<<NIMG, BLK, 0, stream>>>(boxes, scores, out);
}

// Round 8
// 122.540 us; speedup vs baseline: 1.2733x; 1.2733x over previous
//
#include <hip/hip_runtime.h>

#define NBOX   2048
#define MAXDET 100
#define NIMG   8
#define BLK    512
#define NWAVE  (BLK / 64)
#define POOL   512          // boxes held in wave-0 registers (8 per lane)
// midpoint(0.3f, nextafterf(0.3f,+inf)) in double:
// RN_f32(inter/denom) > 0.3f  <=>  inter > IOU_MID * denom
// (25-bit mid x 24-bit denom product exact in f64; tie rounds-to-even to 0.3f -> "false" matches)
#define IOU_MID 0x1.333335p-2

typedef unsigned long long u64;

// padded LDS index for u64 keys: 16 consecutive phys u64 cover all 32 banks once;
// any aligned 16-block is contiguous after padding (needed for 4- and 8-key reads)
__device__ __forceinline__ int KP(int i) { return i + (i >> 4); }
#define KEYSZ (NBOX + NBOX / 16)   // 2176 u64 = 17408 B

#define CMPX(a, b) { if (d ? ((a) < (b)) : ((a) > (b))) { u64 _t = (a); (a) = (b); (b) = _t; } }

#define FOR8(OP) OP(0) OP(1) OP(2) OP(3) OP(4) OP(5) OP(6) OP(7)

__device__ __forceinline__ float readlanef(float v, int src) {
    return __int_as_float(__builtin_amdgcn_readlane(__float_as_int(v), src));
}

__global__ __launch_bounds__(BLK) void region_extractor_kernel(
    const float* __restrict__ boxes,   // [NIMG, NBOX, 4] xyxy
    const float* __restrict__ scores,  // [NIMG, NBOX]
    float* __restrict__ out)           // [NIMG*MAXDET*5] regions ++ [NIMG*MAXDET] mask
{
    __shared__ u64 keys[KEYSZ];            // 17 KB (sorted keys persist for tail path)
    __shared__ float4 leadersB[MAXDET];    // kept boxes (tail-path suppression state)
    __shared__ float  leadersA[MAXDET];    // kept areas

    const int g = threadIdx.x;             // 0..511
    const int b = blockIdx.x;
    const float4* bb4 = (const float4*)(boxes + (size_t)b * NBOX * 4);
    const float*  ss  = scores + (size_t)b * NBOX;

    // ---- Phase A: validity + composite sort key (proven R6 code) --------
    // key = (score_bits << 32) | ~idx : desc sort == (score desc, idx asc);
    // invalid -> hi = 0 (== -inf: sorts last). scores in [0,1): bits monotone.
    for (int p = 0; p < NBOX / BLK; ++p) {
        int i = p * BLK + g;
        float4 v = bb4[i];
        float  s = ss[i];
        bool valid = ((v.z - v.x) >= 25.0f) && ((v.w - v.y) >= 25.0f) && (s >= 0.001f);
        unsigned int sk = valid ? __float_as_uint(s) : 0u;
        keys[KP(i)] = ((u64)sk << 32) | (unsigned int)(~i);
    }
    __syncthreads();

    // ---- Phase B: bitonic sort, descending (proven R6 code) -------------
    {   // fused k=2 (j=1) + k=4 (j=2, j=1): thread g owns aligned block [4g,4g+4)
        int base = KP(4 * g);
        u64 w0 = keys[base], w1 = keys[base + 1], w2 = keys[base + 2], w3 = keys[base + 3];
        { bool d = true;  CMPX(w0, w1) }
        { bool d = false; CMPX(w2, w3) }
        { bool d = ((g & 1) == 0);
          CMPX(w0, w2) CMPX(w1, w3) CMPX(w0, w1) CMPX(w2, w3) }
        keys[base] = w0; keys[base + 1] = w1; keys[base + 2] = w2; keys[base + 3] = w3;
    }
    __syncthreads();

    for (int k = 8; k <= NBOX; k <<= 1) {
        for (int j = k >> 1; j >= 4; j >>= 1) {   // LDS stages
#pragma unroll
            for (int h = 0; h < 2; ++h) {
                int t = h * BLK + g;                       // 0..1023 pair ids
                int i = ((t & ~(j - 1)) << 1) | (t & (j - 1));
                int q = i | j;
                u64 a = keys[KP(i)], c = keys[KP(q)];
                bool swp = ((i & k) == 0) ? (a < c) : (a > c);
                if (swp) { keys[KP(i)] = c; keys[KP(q)] = a; }
            }
            __syncthreads();
        }
        {   // fused j=2, j=1 register pass
            int base = KP(4 * g);
            u64 w0 = keys[base], w1 = keys[base + 1], w2 = keys[base + 2], w3 = keys[base + 3];
            bool d = (((4 * g) & k) == 0);
            CMPX(w0, w2) CMPX(w1, w3) CMPX(w0, w1) CMPX(w2, w3)
            keys[base] = w0; keys[base + 1] = w1; keys[base + 2] = w2; keys[base + 3] = w3;
        }
        __syncthreads();
    }

    // ---- waves 1..7 done: sorted keys are in LDS; wave 0 runs NMS alone --
    if (g >= 64) return;
    const int lane = g;

    // ---- Phase C: wave 0 stages top-POOL boxes in NAMED registers --------
    // lane owns sorted positions 8*lane .. 8*lane+7 (one padded 16-block: contiguous)
#define DECL8(i) float bx1_##i, by1_##i, bx2_##i, by2_##i, bar_##i; u64 q##i;
    FOR8(DECL8)
    unsigned int alive = 0;
    {
        int kb = KP(8 * lane);
#define RDK(i) q##i = keys[kb + i];
        FOR8(RDK)
#define LOAD8(i) { unsigned int idx = ~(unsigned int)q##i;                    \
        float4 v = bb4[idx];                                                  \
        bx1_##i = v.x; by1_##i = v.y; bx2_##i = v.z; by2_##i = v.w;           \
        bar_##i = (v.z - v.x) * (v.w - v.y);                                  \
        if ((unsigned int)(q##i >> 32) != 0u) alive |= (1u << i); }
        FOR8(LOAD8)
    }

    float* regions = out;
    float* maskv   = out + (size_t)NIMG * MAXDET * 5;
    int nkept = 0;

    // ---- Phase D: single-wave NMS — no barriers, no LDS in the loop ------
    while (nkept < MAXDET) {
        u64 bal = __ballot(alive != 0u);
        if (bal == 0ULL) break;                       // pool exhausted -> tail
        int owner = (int)__builtin_ctzll(bal);        // uniform (SGPR)
        unsigned int aw = (unsigned int)__builtin_amdgcn_readlane((int)alive, owner);
        int c = (int)__builtin_ctz(aw);               // uniform slot in owner

        float sx1, sy1, sx2, sy2, sar;                // every lane selects slot c
        switch (c) {                                  // uniform branch
            case 0: sx1=bx1_0; sy1=by1_0; sx2=bx2_0; sy2=by2_0; sar=bar_0; break;
            case 1: sx1=bx1_1; sy1=by1_1; sx2=bx2_1; sy2=by2_1; sar=bar_1; break;
            case 2: sx1=bx1_2; sy1=by1_2; sx2=bx2_2; sy2=by2_2; sar=bar_2; break;
            case 3: sx1=bx1_3; sy1=by1_3; sx2=bx2_3; sy2=by2_3; sar=bar_3; break;
            case 4: sx1=bx1_4; sy1=by1_4; sx2=bx2_4; sy2=by2_4; sar=bar_4; break;
            case 5: sx1=bx1_5; sy1=by1_5; sx2=bx2_5; sy2=by2_5; sar=bar_5; break;
            case 6: sx1=bx1_6; sy1=by1_6; sx2=bx2_6; sy2=by2_6; sar=bar_6; break;
            default: sx1=bx1_7; sy1=by1_7; sx2=bx2_7; sy2=by2_7; sar=bar_7; break;
        }
        float Lx = readlanef(sx1, owner), Ly = readlanef(sy1, owner);
        float Lz = readlanef(sx2, owner), Lw = readlanef(sy2, owner);
        float La = readlanef(sar, owner);             // all uniform broadcasts

        if (lane == 0) {                              // emit + record leader
            float* r = regions + ((size_t)(b * MAXDET + nkept)) * 5;
            r[0] = (float)b; r[1] = Lx; r[2] = Ly; r[3] = Lz; r[4] = Lw;
            maskv[b * MAXDET + nkept] = 1.0f;
            leadersB[nkept] = make_float4(Lx, Ly, Lz, Lw);
            leadersA[nkept] = La;
        }
        nkept++;

        // suppression sweep: 8 register IoU tests; leader self-kills (IoU=1)
        unsigned int kill = 0;
#define TEST8(i) {                                                            \
        float iw = fminf(Lz, bx2_##i) - fmaxf(Lx, bx1_##i);                   \
        float ih = fminf(Lw, by2_##i) - fmaxf(Ly, by1_##i);                   \
        iw = fmaxf(iw, 0.0f); ih = fmaxf(ih, 0.0f);                           \
        float inter = iw * ih;                                                \
        float denom = (La + bar_##i) - inter; /* ref: (a_j + a_i) - inter */  \
        if ((double)inter > IOU_MID * (double)denom) kill |= (1u << i); }
        FOR8(TEST8)
        alive &= ~kill;
    }

    // ---- Tail path (correct for all inputs; rarely taken): positions >= POOL.
    // Greedy NMS suppression comes only from KEPT boxes, so testing each sorted
    // candidate against the <=100 recorded leaders is exact.
    for (int pos = POOL; pos < NBOX && nkept < MAXDET; ++pos) {
        u64 key = keys[KP(pos)];                      // uniform LDS read
        if ((unsigned int)(key >> 32) == 0u) break;   // invalids sort last
        unsigned int idx = ~(unsigned int)key;
        float4 v = bb4[idx];                          // uniform global read
        float varea = (v.z - v.x) * (v.w - v.y);
        bool sup = false;
        for (int t = lane; t < nkept; t += 64) {      // lane tests leaders t, t+64
            float4 Lb = leadersB[t];
            float  La = leadersA[t];
            float iw = fminf(Lb.z, v.z) - fmaxf(Lb.x, v.x);
            float ih = fminf(Lb.w, v.w) - fmaxf(Lb.y, v.y);
            iw = fmaxf(iw, 0.0f); ih = fmaxf(ih, 0.0f);
            float inter = iw * ih;
            float denom = (La + varea) - inter;
            if ((double)inter > IOU_MID * (double)denom) sup = true;
        }
        if (__ballot(sup) == 0ULL) {
            if (lane == 0) {
                float* r = regions + ((size_t)(b * MAXDET + nkept)) * 5;
                r[0] = (float)b; r[1] = v.x; r[2] = v.y; r[3] = v.z; r[4] = v.w;
                maskv[b * MAXDET + nkept] = 1.0f;
                leadersB[nkept] = v;
                leadersA[nkept] = varea;
            }
            nkept++;
        }
    }

    // ---- Phase E: fill padding rows (d_out is poisoned every launch) -----
    for (int r = nkept + lane; r < MAXDET; r += 64) {
        float* rr = regions + ((size_t)(b * MAXDET + r)) * 5;
        rr[0] = (float)b; rr[1] = 0.0f; rr[2] = 0.0f; rr[3] = 0.0f; rr[4] = 0.0f;
        maskv[b * MAXDET + r] = 0.0f;
    }
}

extern "C" void kernel_launch(void* const* d_in, const int* in_sizes, int n_in,
                              void* d_out, int out_size, void* d_ws, size_t ws_size,
                              hipStream_t stream) {
    const float* boxes  = (const float*)d_in[0];  // [8,2048,4] f32
    const float* scores = (const float*)d_in[1];  // [8,2048]   f32
    float* out = (float*)d_out;                   // 4800 f32: regions(4000) ++ mask(800)
    region_extractor_kernel<<<NIMG, BLK, 0, stream>>>(boxes, scores, out);
}

// Round 10
// 110.789 us; speedup vs baseline: 1.4084x; 1.1061x over previous
//
#include <hip/hip_runtime.h>

#define NBOX   2048
#define MAXDET 100
#define NIMG   8
#define BLK    1024
#define POOL   512
// midpoint(0.3f, nextafterf(0.3f,+inf)) in double:
// RN_f32(inter/denom) > 0.3f  <=>  inter > IOU_MID * denom
// (25-bit mid x 24-bit denom product exact in f64; tie rounds-to-even to 0.3f -> "false" matches)
#define IOU_MID 0x1.333335p-2

typedef unsigned long long u64;

// padded LDS index for u64 keys: 16 consecutive phys u64 cover all 32 banks once
__device__ __forceinline__ int KP(int i) { return i + (i >> 4); }
#define KEYSZ (NBOX + NBOX / 16)

#define CMPX(a, b) { if (d ? ((a) < (b)) : ((a) > (b))) { u64 _t = (a); (a) = (b); (b) = _t; } }

__device__ __forceinline__ u64 readlane64(u64 v, int l) {
    unsigned int lo = (unsigned int)__builtin_amdgcn_readlane((int)(unsigned int)v, l);
    unsigned int hi = (unsigned int)__builtin_amdgcn_readlane((int)(v >> 32), l);
    return ((u64)hi << 32) | lo;
}

__global__ __launch_bounds__(BLK) void region_extractor_kernel(
    const float* __restrict__ boxes,
    const float* __restrict__ scores,
    float* __restrict__ out)
{
    __shared__ u64    keys[KEYSZ];        // 17408 B (persists for tail path)
    __shared__ float4 sbox[POOL];         // 8192 B sorted top-512 boxes
    __shared__ u64    supRow[POOL * 8];   // 32768 B suppression matrix (bits j>i only)
    __shared__ u64    validW[8];          // validity bitmask of top-512
    __shared__ float4 leadersB[MAXDET];   // kept boxes (tail-path state)
    __shared__ float  leadersA[MAXDET];   // kept areas

    const int g    = threadIdx.x;         // 0..1023
    const int lane = g & 63;
    const int wv   = g >> 6;              // 0..15
    const int b    = blockIdx.x;
    const float4* bb4 = (const float4*)(boxes + (size_t)b * NBOX * 4);
    const float*  ss  = scores + (size_t)b * NBOX;

    // Phase A: validity + composite sort key.
    // key = (score_bits << 32) | ~idx : desc sort == (score desc, idx asc);
    // invalid -> hi = 0 (sorts last, same as -inf). scores in [0,1): bits monotone.
    for (int p = 0; p < NBOX / BLK; ++p) {
        int i = p * BLK + g;
        float4 v = bb4[i];
        float  s = ss[i];
        bool valid = ((v.z - v.x) >= 25.0f) && ((v.w - v.y) >= 25.0f) && (s >= 0.001f);
        unsigned int sk = valid ? __float_as_uint(s) : 0u;
        keys[KP(i)] = ((u64)sk << 32) | (unsigned int)(~i);
    }
    __syncthreads();

    // Phase B: bitonic sort, descending (R6 structure, 1 pair/thread/stage).
    if (g < NBOX / 4) {   // fused k=2 + k=4 register pass on aligned block [4g,4g+4)
        int base = KP(4 * g);
        u64 w0 = keys[base], w1 = keys[base + 1], w2 = keys[base + 2], w3 = keys[base + 3];
        { bool d = true;  CMPX(w0, w1) }
        { bool d = false; CMPX(w2, w3) }
        { bool d = ((g & 1) == 0);
          CMPX(w0, w2) CMPX(w1, w3) CMPX(w0, w1) CMPX(w2, w3) }
        keys[base] = w0; keys[base + 1] = w1; keys[base + 2] = w2; keys[base + 3] = w3;
    }
    __syncthreads();

    for (int k = 8; k <= NBOX; k <<= 1) {
        for (int j = k >> 1; j >= 4; j >>= 1) {
            int i = ((g & ~(j - 1)) << 1) | (g & (j - 1));
            int q = i | j;
            u64 a = keys[KP(i)], c = keys[KP(q)];
            bool swp = ((i & k) == 0) ? (a < c) : (a > c);
            if (swp) { keys[KP(i)] = c; keys[KP(q)] = a; }
            __syncthreads();
        }
        if (g < NBOX / 4) {   // fused j=2, j=1 register pass
            int base = KP(4 * g);
            u64 w0 = keys[base], w1 = keys[base + 1], w2 = keys[base + 2], w3 = keys[base + 3];
            bool d = (((4 * g) & k) == 0);
            CMPX(w0, w2) CMPX(w1, w3) CMPX(w0, w1) CMPX(w2, w3)
            keys[base] = w0; keys[base + 1] = w1; keys[base + 2] = w2; keys[base + 3] = w3;
        }
        __syncthreads();
    }

    // Phase C: stage top-512 sorted boxes + validity words (waves 0..7).
    if (g < POOL) {
        u64 key = keys[KP(g)];
        unsigned int idx = ~(unsigned int)key;
        float4 v = bb4[idx];
        sbox[g] = v;
        u64 bal = __ballot((unsigned int)(key >> 32) != 0u);
        if (lane == 0) validW[wv] = bal;
    }
    __syncthreads();

    // Column cache: lane holds boxes at sorted positions 64*w + lane, w = 0..7.
    // Constant-indexed after full unroll -> stays in registers (40 VGPRs).
    float4 cb[8];
    float  ca[8];
#pragma unroll
    for (int w = 0; w < 8; ++w) {
        float4 v = sbox[(w << 6) + lane];
        cb[w] = v;
        ca[w] = (v.z - v.x) * (v.w - v.y);
    }

    // Phase D1: parallel suppression-matrix build.
    // Wave wv owns rows i = 16*r + wv (interleaved: balanced load across waves).
    // supRow[i][w] bit l = (64*w + l > i) && IoU(box_i, box_{64w+l}) > 0.3 (exact).
    // Words w < i>>6 are left unwritten: the scan provably never reads them.
    for (int r = 0; r < POOL / 16; ++r) {
        int i = (r << 4) + wv;
        float4 Li = sbox[i];              // wave-uniform broadcast read
        float La = (Li.z - Li.x) * (Li.w - Li.y);
        int w0 = i >> 6;                  // wave-uniform
#pragma unroll
        for (int w = 0; w < 8; ++w) {
            if (w >= w0) {                // wave-uniform condition: ballot is safe
                int j0 = (w << 6) + lane;
                float iw = fminf(Li.z, cb[w].z) - fmaxf(Li.x, cb[w].x);
                float ih = fminf(Li.w, cb[w].w) - fmaxf(Li.y, cb[w].y);
                iw = fmaxf(iw, 0.0f);
                ih = fmaxf(ih, 0.0f);
                float inter = iw * ih;
                float denom = (La + ca[w]) - inter;   // ref op order: (a_i + a_j) - inter
                bool hit = (j0 > i) && ((double)inter > IOU_MID * (double)denom);
                u64 bits = __ballot(hit);
                if (lane == 0) supRow[(i << 3) + w] = bits;
            }
        }
    }
    __syncthreads();

    if (g >= 64) return;   // wave 0 finishes alone; no barriers below

    float* regions = out;
    float* maskv   = out + (size_t)NIMG * MAXDET * 5;
    int nkept = 0;

    // Phase D2: serial scan; suppressed positions cost zero (bulk mask clear).
    // Lane l accumulates pending-suppression word (l & 7) in pend.
    u64 pend = 0;
    bool done = false;
    for (int s = 0; s < 8 && !done; ++s) {
        u64 V = validW[s];
        u64 m = V & ~readlane64(pend, s);
        while (m) {
            int il = (int)__builtin_ctzll(m);
            int i = (s << 6) + il;                     // next leader in greedy order
            u64 rowv = supRow[(i << 3) + (lane & 7)];  // 8 distinct words, broadcast groups
            float4 Lb = sbox[i];
            if (lane == 0) {
                float* rr = regions + ((size_t)(b * MAXDET + nkept)) * 5;
                rr[0] = (float)b; rr[1] = Lb.x; rr[2] = Lb.y; rr[3] = Lb.z; rr[4] = Lb.w;
                maskv[b * MAXDET + nkept] = 1.0f;
                leadersB[nkept] = Lb;
                leadersA[nkept] = (Lb.z - Lb.x) * (Lb.w - Lb.y);
            }
            nkept++;
            if (nkept >= MAXDET) { done = true; break; }
            pend |= rowv;                              // fold leader's suppressions
            m = (m & (m - 1)) & ~readlane64(pend, s);
        }
    }

    // Tail (exact, rarely taken): positions >= POOL tested vs recorded leaders.
    // Greedy NMS suppression comes only from kept boxes, so this is sufficient state.
    for (int pos = POOL; pos < NBOX && nkept < MAXDET; ++pos) {
        u64 key = keys[KP(pos)];
        if ((unsigned int)(key >> 32) == 0u) break;    // invalids sort last
        unsigned int idx = ~(unsigned int)key;
        float4 v = bb4[idx];
        float varea = (v.z - v.x) * (v.w - v.y);
        bool sup = false;
        for (int t = lane; t < nkept; t += 64) {
            float4 Lb = leadersB[t];
            float  La = leadersA[t];
            float iw = fminf(Lb.z, v.z) - fmaxf(Lb.x, v.x);
            float ih = fminf(Lb.w, v.w) - fmaxf(Lb.y, v.y);
            iw = fmaxf(iw, 0.0f);
            ih = fmaxf(ih, 0.0f);
            float inter = iw * ih;
            float denom = (La + varea) - inter;
            if ((double)inter > IOU_MID * (double)denom) sup = true;
        }
        if (__ballot(sup) == 0ULL) {
            if (lane == 0) {
                float* rr = regions + ((size_t)(b * MAXDET + nkept)) * 5;
                rr[0] = (float)b; rr[1] = v.x; rr[2] = v.y; rr[3] = v.z; rr[4] = v.w;
                maskv[b * MAXDET + nkept] = 1.0f;
                leadersB[nkept] = v;
                leadersA[nkept] = varea;
            }
            nkept++;
        }
    }

    // Phase E: fill padding rows (d_out is poisoned before every launch).
    for (int r = nkept + lane; r < MAXDET; r += 64) {
        float* rr = regions + ((size_t)(b * MAXDET + r)) * 5;
        rr[0] = (float)b; rr[1] = 0.0f; rr[2] = 0.0f; rr[3] = 0.0f; rr[4] = 0.0f;
        maskv[b * MAXDET + r] = 0.0f;
    }
}

extern "C" void kernel_launch(void* const* d_in, const int* in_sizes, int n_in,
                              void* d_out, int out_size, void* d_ws, size_t ws_size,
                              hipStream_t stream) {
    const float* boxes  = (const float*)d_in[0];  // [8,2048,4] f32
    const float* scores = (const float*)d_in[1];  // [8,2048]   f32
    float* out = (float*)d_out;                   // 4800 f32: regions(4000) ++ mask(800)
    region_extractor_kernel<<<NIMG, BLK, 0, stream>>>(boxes, scores, out);
}